// Round 9
// baseline (189.986 us; speedup 1.0000x reference)
//
#include <hip/hip_runtime.h>
#include <math.h>

#define NS 4096
#define DD 768
#define NH 30          // N_HIPER
#define NCH 31         // channels per cell
#define NCELL 81       // 9x9 grid
#define NBLK 256       // chunk blocks
#define NTHR 384       // threads (each owns 2 d's)
#define CS 16          // samples per chunk = NS/NBLK
#define WFB 96         // waccfinal blocks (96*8 = 768 d's)
#define WS 8           // d-slice width per block
#define WFT 512        // waccfinal threads (64 sample-lanes x 8 d-lanes)

// ---------------------------------------------------------------------------
// k1 pass1: prep + density gather + chunk-local u[s,d] = E*(1-exp(-dd))
//           (telescoping) + chunk attenuation E[c,d]. Writes cells/coefs.
// ---------------------------------------------------------------------------
__global__ __launch_bounds__(NTHR) void pass1_kernel(
    const float* __restrict__ samples, const float* __restrict__ last_point,
    const float* __restrict__ emb,
    int4* __restrict__ cells, float4* __restrict__ coefs,
    float* __restrict__ u, float* __restrict__ Ebuf)
{
    __shared__ int4   s_cells[CS];
    __shared__ float4 s_coefs[CS];
    __shared__ float  s_dist[CS];

    const int t  = threadIdx.x;
    const int b  = blockIdx.x;
    const int d0 = 2*t;

    if (t < CS) {
        const int s = b*CS + t;
        float x = samples[2*s+0], y = samples[2*s+1];
        float xs = x + 4.0f, ys = y + 4.0f;
        int fx = (int)floorf(xs), cx = (int)ceilf(xs);
        int fy = (int)floorf(ys), cy = (int)ceilf(ys);
        float dx = x - floorf(x), dy = y - floorf(y);
        float nx, ny;
        if (s == NS-1) { nx = last_point[0]; ny = last_point[1]; }
        else           { nx = samples[2*s+2]; ny = samples[2*s+3]; }
        float ex = nx - x, ey = ny - y;
        s_dist[t] = sqrtf(ex*ex + ey*ey);
        int4 cl = make_int4(fx*9+fy, cx*9+fy, fx*9+cy, cx*9+cy);
        float4 cf = make_float4((1.f-dx)*(1.f-dy), dx*(1.f-dy),
                                (1.f-dx)*dy,       dx*dy);
        s_cells[t] = cl; s_coefs[t] = cf;
        cells[s] = cl;   coefs[s]  = cf;     // for waccfinal
    }
    __syncthreads();

    float Ex = 1.f, Ey = 1.f;
    #pragma unroll
    for (int i = 0; i < CS; ++i) {
        int4 cl = s_cells[i]; float4 cf = s_coefs[i]; float dist = s_dist[i];
        const int off = NH*DD + d0;
        float2 e0 = *(const float2*)(emb + cl.x*NCH*DD + off);
        float2 e1 = *(const float2*)(emb + cl.y*NCH*DD + off);
        float2 e2 = *(const float2*)(emb + cl.z*NCH*DD + off);
        float2 e3 = *(const float2*)(emb + cl.w*NCH*DD + off);
        float vx = e0.x*cf.x + e1.x*cf.y + e2.x*cf.z + e3.x*cf.w;
        float vy = e0.y*cf.x + e1.y*cf.y + e2.y*cf.z + e3.y*cf.w;
        float fx_ = __expf(-fmaxf(vx, 0.f) * dist);
        float fy_ = __expf(-fmaxf(vy, 0.f) * dist);
        *(float2*)(u + (b*CS + i)*DD + d0) =
            make_float2(Ex*(1.f - fx_), Ey*(1.f - fy_));
        Ex *= fx_; Ey *= fy_;
    }
    *(float2*)(Ebuf + b*DD + d0) = make_float2(Ex, Ey);
}

// ---------------------------------------------------------------------------
// k2 scan: exclusive PRODUCT scan of E over 256 chunks per d -> scale[c,d]
// ---------------------------------------------------------------------------
__global__ __launch_bounds__(64) void scan_kernel(
    const float* __restrict__ Ebuf, float* __restrict__ scale) {
    const int d    = blockIdx.x;       // 0..767
    const int lane = threadIdx.x;      // 0..63
    float v[4];
    float tot = 1.f;
    #pragma unroll
    for (int k = 0; k < 4; ++k) {
        v[k] = Ebuf[(lane*4 + k)*DD + d];
        tot *= v[k];
    }
    float x = tot;
    #pragma unroll
    for (int off = 1; off < 64; off <<= 1) {
        float y = __shfl_up(x, off);
        if (lane >= off) x *= y;
    }
    float run = __shfl_up(x, 1);
    if (lane == 0) run = 1.f;
    #pragma unroll
    for (int k = 0; k < 4; ++k) {
        scale[(lane*4 + k)*DD + d] = run;
        run *= v[k];
    }
}

// ---------------------------------------------------------------------------
// k3 waccfinal: per-block d-slice of width 8; W[81][8] lives in LDS; every
//               sample scatters its 4 corner contributions via LDS atomics;
//               then out[n,d] = sum_g W[g,d]*T[g,n,d] directly. No global W.
// ---------------------------------------------------------------------------
__global__ __launch_bounds__(WFT) void waccfinal_kernel(
    const int4* __restrict__ cells, const float4* __restrict__ coefs,
    const float* __restrict__ u, const float* __restrict__ scale,
    const float* __restrict__ emb, float* __restrict__ out)
{
    __shared__ float Wl[NCELL][WS + 1];   // +1 pad: (g*9+dl)%32 hits all banks

    const int lane = threadIdx.x;
    const int dl   = lane & (WS - 1);     // 0..7
    const int sg   = lane >> 3;           // 0..63
    const int d    = blockIdx.x * WS + dl;

    for (int i = lane; i < NCELL*(WS+1); i += WFT)
        ((float*)Wl)[i] = 0.f;
    __syncthreads();

    #pragma unroll 4
    for (int s = sg; s < NS; s += WFT/WS) {
        int4   cl = cells[s];
        float4 cf = coefs[s];
        const int ch = s >> 4;            // s / CS
        float wv = scale[ch*DD + d] * u[(long)s*DD + d];
        atomicAdd(&Wl[cl.x][dl], cf.x * wv);
        atomicAdd(&Wl[cl.y][dl], cf.y * wv);
        atomicAdd(&Wl[cl.z][dl], cf.z * wv);
        atomicAdd(&Wl[cl.w][dl], cf.w * wv);
    }
    __syncthreads();

    if (lane < NH*WS) {
        const int n = lane >> 3;          // 0..29
        float a0 = 0.f, a1 = 0.f, a2 = 0.f;
        #pragma unroll 3
        for (int g = 0; g < NCELL; g += 3) {
            a0 += Wl[g+0][dl] * emb[((g+0)*NCH + n)*DD + d];
            a1 += Wl[g+1][dl] * emb[((g+1)*NCH + n)*DD + d];
            a2 += Wl[g+2][dl] * emb[((g+2)*NCH + n)*DD + d];
        }
        out[n*DD + d] = (a0 + a1) + a2;
    }
}

// ---------------------------------------------------------------------------
extern "C" void kernel_launch(void* const* d_in, const int* in_sizes, int n_in,
                              void* d_out, int out_size, void* d_ws, size_t ws_size,
                              hipStream_t stream) {
    const float* samples    = (const float*)d_in[0];
    const float* last_point = (const float*)d_in[1];
    const float* emb        = (const float*)d_in[2];
    float* out = (float*)d_out;

    char* ws = (char*)d_ws;
    int4*   cells = (int4*)ws;     ws += (size_t)NS*sizeof(int4);
    float4* coefs = (float4*)ws;   ws += (size_t)NS*sizeof(float4);
    float*  Ebuf  = (float*)ws;    ws += (size_t)NBLK*DD*sizeof(float);
    float*  scale = (float*)ws;    ws += (size_t)NBLK*DD*sizeof(float);
    float*  umat  = (float*)ws;    ws += (size_t)NS*DD*sizeof(float);

    pass1_kernel<<<NBLK, NTHR, 0, stream>>>(samples, last_point, emb,
                                            cells, coefs, umat, Ebuf);
    scan_kernel<<<DD, 64, 0, stream>>>(Ebuf, scale);
    waccfinal_kernel<<<WFB, WFT, 0, stream>>>(cells, coefs, umat, scale,
                                              emb, out);
}

// Round 10
// 34.545 us; speedup vs baseline: 5.4997x; 5.4997x over previous
//
#include <hip/hip_runtime.h>
#include <math.h>

#define NS 4096
#define DD 768
#define NH 30          // N_HIPER
#define NCH 31         // channels per cell
#define NCELL 81       // 9x9 grid
#define NBLK 256       // chunk blocks
#define NTHR 384       // threads (each owns 2 d's)
#define CS 16          // samples per chunk = NS/NBLK
#define NPART 8        // sample partitions for wacc
#define SPP 512        // NS/NPART
#define NW (NCELL*DD)
#define NACC (NCELL*NPART)   // 648 wacc blocks

// ---------------------------------------------------------------------------
// k1 pass1: prep + density gather + dd -> global + chunk sums.
//           Also zeroes W and writes cells/coefs for wacc.  (r6-identical)
// ---------------------------------------------------------------------------
__global__ __launch_bounds__(NTHR) void pass1_kernel(
    const float* __restrict__ samples, const float* __restrict__ last_point,
    const float* __restrict__ emb,
    int4* __restrict__ cells, float4* __restrict__ coefs,
    float* __restrict__ ddbuf, float* __restrict__ chunk_sum,
    float* __restrict__ W)
{
    __shared__ int4   s_cells[CS];
    __shared__ float4 s_coefs[CS];
    __shared__ float  s_dist[CS];

    const int t  = threadIdx.x;
    const int b  = blockIdx.x;
    const int d0 = 2*t;

    if (t < CS) {
        const int s = b*CS + t;
        float x = samples[2*s+0], y = samples[2*s+1];
        float xs = x + 4.0f, ys = y + 4.0f;
        int fx = (int)floorf(xs), cx = (int)ceilf(xs);
        int fy = (int)floorf(ys), cy = (int)ceilf(ys);
        float dx = x - floorf(x), dy = y - floorf(y);
        float nx, ny;
        if (s == NS-1) { nx = last_point[0]; ny = last_point[1]; }
        else           { nx = samples[2*s+2]; ny = samples[2*s+3]; }
        float ex = nx - x, ey = ny - y;
        s_dist[t] = sqrtf(ex*ex + ey*ey);
        int4 cl = make_int4(fx*9+fy, cx*9+fy, fx*9+cy, cx*9+cy);
        float4 cf = make_float4((1.f-dx)*(1.f-dy), dx*(1.f-dy),
                                (1.f-dx)*dy,       dx*dy);
        s_cells[t] = cl; s_coefs[t] = cf;
        cells[s] = cl;   coefs[s]  = cf;     // for wacc
    }
    { int g = b*NTHR + t; if (g < NW) W[g] = 0.f; }   // zero W, no memset
    __syncthreads();

    float sx = 0.f, sy = 0.f;
    #pragma unroll
    for (int i = 0; i < CS; ++i) {
        int4 cl = s_cells[i]; float4 cf = s_coefs[i]; float dist = s_dist[i];
        const int off = NH*DD + d0;
        float2 e0 = *(const float2*)(emb + cl.x*NCH*DD + off);
        float2 e1 = *(const float2*)(emb + cl.y*NCH*DD + off);
        float2 e2 = *(const float2*)(emb + cl.z*NCH*DD + off);
        float2 e3 = *(const float2*)(emb + cl.w*NCH*DD + off);
        float vx = e0.x*cf.x + e1.x*cf.y + e2.x*cf.z + e3.x*cf.w;
        float vy = e0.y*cf.x + e1.y*cf.y + e2.y*cf.z + e3.y*cf.w;
        float ddx = fmaxf(vx, 0.f) * dist;
        float ddy = fmaxf(vy, 0.f) * dist;
        *(float2*)(ddbuf + (b*CS + i)*DD + d0) = make_float2(ddx, ddy);
        sx += ddx; sy += ddy;
    }
    *(float2*)(chunk_sum + b*DD + d0) = make_float2(sx, sy);
}

// ---------------------------------------------------------------------------
// k2 scan: exclusive prefix over 256 chunks per d; one wave per d (r6-identical)
// ---------------------------------------------------------------------------
__global__ __launch_bounds__(64) void scan_kernel(
    const float* __restrict__ chunk_sum, float* __restrict__ offs) {
    const int d    = blockIdx.x;       // 0..767
    const int lane = threadIdx.x;      // 0..63
    float v[4];
    #pragma unroll
    for (int k = 0; k < 4; ++k)
        v[k] = chunk_sum[(lane*4 + k)*DD + d];
    float tot = (v[0] + v[1]) + (v[2] + v[3]);
    float x = tot;
    #pragma unroll
    for (int off = 1; off < 64; off <<= 1) {
        float y = __shfl_up(x, off);
        if (lane >= off) x += y;
    }
    float run = x - tot;   // exclusive prefix of this lane's group
    #pragma unroll
    for (int k = 0; k < 4; ++k) {
        offs[(lane*4 + k)*DD + d] = run;
        run += v[k];
    }
}

// ---------------------------------------------------------------------------
// k3 w: w[s,d] = exp(-cum_excl)*(1-exp(-dd)), telescoping (r6-identical)
// ---------------------------------------------------------------------------
__global__ __launch_bounds__(NTHR) void w_kernel(
    const float* __restrict__ ddbuf, const float* __restrict__ offs,
    float* __restrict__ w) {
    const int t  = threadIdx.x;
    const int b  = blockIdx.x;
    const int d0 = 2*t;
    float2 cum = *(const float2*)(offs + b*DD + d0);
    float Ex = __expf(-cum.x), Ey = __expf(-cum.y);
    #pragma unroll
    for (int i = 0; i < CS; ++i) {
        float2 dd = *(const float2*)(ddbuf + (b*CS + i)*DD + d0);
        float fx = __expf(-dd.x), fy = __expf(-dd.y);
        *(float2*)(w + (b*CS + i)*DD + d0) =
            make_float2(Ex * (1.f - fx), Ey * (1.f - fy));
        Ex *= fx; Ey *= fy;
    }
}

// ---------------------------------------------------------------------------
// k4 wacc: W[g,d] += sum over samples with corner g of coef*w[s,d]
//          4-way unrolled j-loop, 4 independent accumulator triples (NEW)
// ---------------------------------------------------------------------------
__global__ __launch_bounds__(256) void wacc_kernel(
    const int4* __restrict__ cells, const float4* __restrict__ coefs,
    const float* __restrict__ w, float* __restrict__ W) {
    __shared__ int   s_idx[SPP];
    __shared__ float s_cf[SPP];
    __shared__ int   s_cnt;
    const int g    = blockIdx.x / NPART;
    const int part = blockIdx.x % NPART;
    const int t    = threadIdx.x;
    if (t == 0) s_cnt = 0;
    __syncthreads();
    const int s_beg = part * SPP;
    #pragma unroll
    for (int i = 0; i < SPP; i += 256) {
        const int s = s_beg + i + t;
        int4 cl = cells[s]; float4 cf = coefs[s];
        float c = 0.f;
        if (cl.x == g) c += cf.x;
        if (cl.y == g) c += cf.y;
        if (cl.z == g) c += cf.z;
        if (cl.w == g) c += cf.w;
        if (c != 0.f) {
            int idx = atomicAdd(&s_cnt, 1);
            s_idx[idx] = s;
            s_cf[idx]  = c;
        }
    }
    __syncthreads();
    const int cnt = s_cnt;

    float a00=0.f, a01=0.f, a02=0.f;
    float a10=0.f, a11=0.f, a12=0.f;
    float a20=0.f, a21=0.f, a22=0.f;
    float a30=0.f, a31=0.f, a32=0.f;
    int j = 0;
    for (; j + 4 <= cnt; j += 4) {
        const float* w0 = w + (long)s_idx[j+0]*DD;
        const float* w1 = w + (long)s_idx[j+1]*DD;
        const float* w2 = w + (long)s_idx[j+2]*DD;
        const float* w3 = w + (long)s_idx[j+3]*DD;
        const float c0 = s_cf[j+0], c1 = s_cf[j+1];
        const float c2 = s_cf[j+2], c3 = s_cf[j+3];
        // issue all 12 loads, then FMA into 4 independent chains
        float v00 = w0[t], v01 = w0[t+256], v02 = w0[t+512];
        float v10 = w1[t], v11 = w1[t+256], v12 = w1[t+512];
        float v20 = w2[t], v21 = w2[t+256], v22 = w2[t+512];
        float v30 = w3[t], v31 = w3[t+256], v32 = w3[t+512];
        a00 += c0*v00; a01 += c0*v01; a02 += c0*v02;
        a10 += c1*v10; a11 += c1*v11; a12 += c1*v12;
        a20 += c2*v20; a21 += c2*v21; a22 += c2*v22;
        a30 += c3*v30; a31 += c3*v31; a32 += c3*v32;
    }
    for (; j < cnt; ++j) {
        const float* wr = w + (long)s_idx[j]*DD;
        const float  c  = s_cf[j];
        a00 += c*wr[t]; a01 += c*wr[t+256]; a02 += c*wr[t+512];
    }
    const float r0 = (a00 + a10) + (a20 + a30);
    const float r1 = (a01 + a11) + (a21 + a31);
    const float r2 = (a02 + a12) + (a22 + a32);
    atomicAdd(&W[g*DD + t      ], r0);
    atomicAdd(&W[g*DD + t + 256], r1);
    atomicAdd(&W[g*DD + t + 512], r2);
}

// ---------------------------------------------------------------------------
// k5 final: out[n,d] = sum_g W[g,d] * T[g,n,d]  (r6-identical)
// ---------------------------------------------------------------------------
__global__ __launch_bounds__(256) void final_kernel(
    const float* __restrict__ emb, const float* __restrict__ W,
    float* __restrict__ out) {
    const int n    = blockIdx.x / 3;
    const int part = blockIdx.x % 3;
    const int d    = part*256 + threadIdx.x;
    float a0 = 0.f, a1 = 0.f, a2 = 0.f, a3 = 0.f;
    int g = 0;
    #pragma unroll 4
    for (; g + 4 <= 80; g += 4) {
        a0 += W[(g+0)*DD + d] * emb[((g+0)*NCH + n)*DD + d];
        a1 += W[(g+1)*DD + d] * emb[((g+1)*NCH + n)*DD + d];
        a2 += W[(g+2)*DD + d] * emb[((g+2)*NCH + n)*DD + d];
        a3 += W[(g+3)*DD + d] * emb[((g+3)*NCH + n)*DD + d];
    }
    a0 += W[80*DD + d] * emb[(80*NCH + n)*DD + d];
    out[n*DD + d] = (a0 + a1) + (a2 + a3);
}

// ---------------------------------------------------------------------------
extern "C" void kernel_launch(void* const* d_in, const int* in_sizes, int n_in,
                              void* d_out, int out_size, void* d_ws, size_t ws_size,
                              hipStream_t stream) {
    const float* samples    = (const float*)d_in[0];
    const float* last_point = (const float*)d_in[1];
    const float* emb        = (const float*)d_in[2];
    float* out = (float*)d_out;

    char* ws = (char*)d_ws;
    int4*   cells  = (int4*)ws;     ws += (size_t)NS*sizeof(int4);
    float4* coefs  = (float4*)ws;   ws += (size_t)NS*sizeof(float4);
    float*  chunk_sum = (float*)ws; ws += (size_t)NBLK*DD*sizeof(float);
    float*  offs   = (float*)ws;    ws += (size_t)NBLK*DD*sizeof(float);
    float*  Wbuf   = (float*)ws;    ws += (size_t)NW*sizeof(float);
    float*  ddbuf  = (float*)ws;    ws += (size_t)NS*DD*sizeof(float);
    float*  wmat   = (float*)ws;    ws += (size_t)NS*DD*sizeof(float);

    pass1_kernel<<<NBLK, NTHR, 0, stream>>>(samples, last_point, emb,
                                            cells, coefs, ddbuf, chunk_sum,
                                            Wbuf);
    scan_kernel<<<DD, 64, 0, stream>>>(chunk_sum, offs);
    w_kernel<<<NBLK, NTHR, 0, stream>>>(ddbuf, offs, wmat);
    wacc_kernel<<<NACC, 256, 0, stream>>>(cells, coefs, wmat, Wbuf);
    final_kernel<<<NH*3, 256, 0, stream>>>(emb, Wbuf, out);
}